// Round 11
// baseline (159.433 us; speedup 1.0000x reference)
//
#include <hip/hip_runtime.h>

// Sizes (fixed for this problem)
constexpr int B  = 2,  CIN = 2,  H = 64, W = 64, T = 350;
constexpr int C1 = 8;                       // conv1 out channels
constexpr int TO = 700, HO = 128, WO = 64;
constexpr int HW = H * W;                   // 4096

#define DEC 0.05000000074505806f            // (float)(1.0 - 0.95)

// ---------------------------------------------------------------------------
// Kernel 0: transpose x [B,2,H,W,T] -> xT [B,2,T,H,W] so conv reads coalesce.
// ---------------------------------------------------------------------------
__global__ void __launch_bounds__(256) transpose_kernel(
    const float* __restrict__ x, float* __restrict__ xT) {
  __shared__ float tile[64][65];
  int bid   = blockIdx.x;
  int tTile = bid % 6;            // 6 tiles of 64 cover T=350
  int slice = bid / 6;            // (b*2+ci)*64 + h
  int h  = slice % H;
  int bc = slice / H;             // b*2+ci
  int t0 = tTile * 64;
  int tx = threadIdx.x & 63;
  int tz = threadIdx.x >> 6;      // 0..3

  const float* src = x + ((long)bc * H + h) * (long)(W * T);
#pragma unroll
  for (int i = 0; i < 16; ++i) {
    int w = tz * 16 + i;
    int t = t0 + tx;
    tile[w][tx] = (t < T) ? src[(long)w * T + t] : 0.0f;
  }
  __syncthreads();
  float* dst = xT + ((long)bc * T) * HW + h * 64;
#pragma unroll
  for (int i = 0; i < 16; ++i) {
    int tl = tz * 16 + i;
    int t  = t0 + tl;
    if (t < T) dst[(long)t * HW + tx] = tile[tx][tl];
  }
}

// ---------------------------------------------------------------------------
// async global->LDS, 16 bytes per lane (wave-uniform LDS base + lane*16)
// ---------------------------------------------------------------------------
__device__ __forceinline__ void gload_lds16(const float* g, float* l) {
  __builtin_amdgcn_global_load_lds(
      (const __attribute__((address_space(1))) unsigned int*)g,
      (__attribute__((address_space(3))) unsigned int*)l, 16, 0, 0);
}

// ---------------------------------------------------------------------------
// Kernel A1 (SPLIT PATH): conv1(5x5) + bias + relu -> A fp32 [b][t][hw][co].
// NO serial chain: grid (b, tile of 12 t's, h) = 2*30*64 = 3840 independent
// blocks. block = 512 = (w 0..63) x (co 0..7), tid = w*8+co so A stores are
// lane-contiguous (256B/wave). LDS: single 160-row buffer [tau-major x
// (ci,dh)] staged by 5 gload_lds16 issues; reads are 8-addr broadcasts
// (conflict-free). Sliding 4-slot register window + per-step fresh read.
// ---------------------------------------------------------------------------
__global__ void __launch_bounds__(512) convpar_kernel(
    const float* __restrict__ xT, const float* __restrict__ w1,
    const float* __restrict__ b1, float* __restrict__ A) {
  __shared__ float lb[160 * 64];            // 40 KiB
  const int tid  = threadIdx.x;
  const int bid  = blockIdx.x;
  const int h    = bid & 63;
  const int rest = bid >> 6;
  const int tile = rest % 30;
  const int b    = rest / 30;
  const int t0   = tile * 12;
  const int co   = tid & 7;
  const int w    = tid >> 3;                // 0..63
  const int wid  = tid >> 6;                // wave id 0..7

  // Weights per thread (co per-lane -> VGPR); zero taps whose h+dh-2 is OOB.
  float wt[2][5][5];
#pragma unroll
  for (int ci = 0; ci < 2; ++ci)
#pragma unroll
    for (int dh = 0; dh < 5; ++dh) {
      int hh = h + dh - 2;
      bool hv = (hh >= 0) && (hh < H);
#pragma unroll
      for (int dt = 0; dt < 5; ++dt)
        wt[ci][dt][dh] = hv ? w1[((co * 2 + ci) * 5 + dt) * 5 + dh] : 0.0f;
    }
  float bias = b1[co];

  // Staging: 5 issues x 32 rows cover rows 0..159 exactly (no pad rows).
  // row r = j*10 + ci*5 + dh holds tau = t0-2+j (j in [0,16)).
  int cdesc[5];
#pragma unroll
  for (int i = 0; i < 5; ++i) {
    int r   = (tid >> 4) + 32 * i;          // 0..159
    int j   = r / 10;
    int rem = r - j * 10;
    int ci  = rem / 5;
    int dh  = rem - ci * 5;
    int hh = h + dh - 2;
    int hc = hh < 0 ? 0 : (hh > H - 1 ? H - 1 : hh);
    cdesc[i] = (((b * 2 + ci) * T) * HW + hc * 64 + (tid & 15) * 4) | (j << 27);
  }
#pragma unroll
  for (int i = 0; i < 5; ++i) {
    int tau = t0 - 2 + (cdesc[i] >> 27);
    tau = tau < 0 ? 0 : (tau > T - 1 ? T - 1 : tau);
    gload_lds16(xT + (long)(cdesc[i] & 0x07ffffff) + (long)tau * HW,
                &lb[(i * 32 + wid * 4) * 64]);
  }
  __syncthreads();                          // staging complete

  // Zero rows whose tau is outside [0,T) (tile 0 head, tile 29 tail).
  {
    int rlo = (t0 >= 2) ? 0 : (2 - t0) * 10;            // invalid rows [0,rlo)
    int rhiv = (T - t0 + 2) * 10;                       // first invalid tail row
    int rhi = rhiv > 160 ? 160 : rhiv;                  // valid rows [rlo,rhi)
    if (rlo > 0 || rhi < 160) {
      for (int s = tid; s < rlo * 64; s += 512) lb[s] = 0.0f;
      for (int s = rhi * 64 + tid; s < 160 * 64; s += 512) lb[s] = 0.0f;
      __syncthreads();
    }
  }

  // Window init from LDS: taus t0-2..t0+1 = rows 0,10,20,30 (+cidh).
  float win[2][5][4];
#pragma unroll
  for (int ci = 0; ci < 2; ++ci)
#pragma unroll
    for (int dh = 0; dh < 5; ++dh) {
      const int cd = ci * 5 + dh;
      win[ci][dh][2] = lb[(0  + cd) * 64 + w];   // tau t0-2 (slot (t0-2)&3=2)
      win[ci][dh][3] = lb[(10 + cd) * 64 + w];   // tau t0-1
      win[ci][dh][0] = lb[(20 + cd) * 64 + w];   // tau t0
      win[ci][dh][1] = lb[(30 + cd) * 64 + w];   // tau t0+1
    }

  float* const Abase = A + (((long)(b * T)) * HW + h * 64 + w) * 8 + co;
#pragma unroll
  for (int u = 0; u < 12; ++u) {
    int t = t0 + u;
    // fresh read: tau = t+2 at row (u+4)*10 + cidh
    float fr[2][5];
#pragma unroll
    for (int ci = 0; ci < 2; ++ci)
#pragma unroll
      for (int dh = 0; dh < 5; ++dh)
        fr[ci][dh] = lb[((u + 4) * 10 + ci * 5 + dh) * 64 + w];

    float ac0 = 0.f, ac1 = 0.f, ac2 = 0.f, ac3 = 0.f;
#pragma unroll
    for (int ci = 0; ci < 2; ++ci)
#pragma unroll
      for (int dt = 0; dt < 5; ++dt)
#pragma unroll
        for (int dh = 0; dh < 5; ++dh) {
          const int q = (ci * 25 + dt * 5 + dh) & 3;
          float tap = (dt < 4) ? win[ci][dh][(u + 2 + dt) & 3] : fr[ci][dh];
          float p = tap * wt[ci][dt][dh];
          if (q == 0) ac0 += p;
          else if (q == 1) ac1 += p;
          else if (q == 2) ac2 += p;
          else ac3 += p;
        }
    float a = ((ac0 + ac1) + (ac2 + ac3)) + bias;
    a = fmaxf(a, 0.0f);
    if (t < T) Abase[(long)t * (HW * C1)] = a;
    // window advance
#pragma unroll
    for (int ci = 0; ci < 2; ++ci)
#pragma unroll
      for (int dh = 0; dh < 5; ++dh)
        win[ci][dh][(u + 2) & 3] = fr[ci][dh];
  }
}

// ---------------------------------------------------------------------------
// Kernel A2 (SPLIT PATH): LIF1 + delta over A -> d8 int8 [b][t][hw][ci].
// Pure streaming scan: thread = (b, hw) owns all 8 co. 8 T-chunks x 16-warm
// (0.05^16 ~ 1e-21, bitwise-converged -- proven r3-r10). Per step: 32B
// float4x2 load (prefetched 1 iter ahead, stage2's proven pattern), 8 LIF
// updates, one 8B packed delta store.
// ---------------------------------------------------------------------------
__global__ void __launch_bounds__(256) lif_kernel(
    const float* __restrict__ A, signed char* __restrict__ d8) {
  const int tid   = threadIdx.x;
  const int bid   = blockIdx.x;
  const int chunk = bid & 7;
  const int hwh   = (bid >> 3) & 15;
  const int b     = bid >> 7;
  const int hw    = hwh * 256 + tid;

  const int t0 = chunk * 44;
  const int te = (t0 + 44 < T) ? t0 + 44 : T;
  const int tw = (t0 >= 16) ? t0 - 16 : 0;

  const float4* Ab = reinterpret_cast<const float4*>(
      A + (((long)(b * T)) * HW + hw) * 8);
  const long ts4 = (long)HW * 2;            // float4 stride per t
  signed char* db = d8 + (((long)(b * T)) * HW + hw) * 8;
  const long tsb = (long)HW * 8;

  float y0=0,y1=0,y2=0,y3=0,y4=0,y5=0,y6=0,y7=0;
  float p0=0,p1=0,p2=0,p3=0,p4=0,p5=0,p6=0,p7=0;   // prev spikes

  float4 a0 = Ab[(long)tw * ts4];
  float4 a1 = Ab[(long)tw * ts4 + 1];
  for (int t = tw; t < te; ++t) {
    int tn = (t + 1 < te) ? t + 1 : t;
    float4 n0 = Ab[(long)tn * ts4];
    float4 n1 = Ab[(long)tn * ts4 + 1];

    float s0,s1,s2,s3,s4,s5,s6,s7;
    y0 = fmaf(DEC, y0, a0.x); s0 = (y0 >= 1.0f) ? 1.0f : 0.0f; y0 = (s0!=0.0f)?0.0f:y0;
    y1 = fmaf(DEC, y1, a0.y); s1 = (y1 >= 1.0f) ? 1.0f : 0.0f; y1 = (s1!=0.0f)?0.0f:y1;
    y2 = fmaf(DEC, y2, a0.z); s2 = (y2 >= 1.0f) ? 1.0f : 0.0f; y2 = (s2!=0.0f)?0.0f:y2;
    y3 = fmaf(DEC, y3, a0.w); s3 = (y3 >= 1.0f) ? 1.0f : 0.0f; y3 = (s3!=0.0f)?0.0f:y3;
    y4 = fmaf(DEC, y4, a1.x); s4 = (y4 >= 1.0f) ? 1.0f : 0.0f; y4 = (s4!=0.0f)?0.0f:y4;
    y5 = fmaf(DEC, y5, a1.y); s5 = (y5 >= 1.0f) ? 1.0f : 0.0f; y5 = (s5!=0.0f)?0.0f:y5;
    y6 = fmaf(DEC, y6, a1.z); s6 = (y6 >= 1.0f) ? 1.0f : 0.0f; y6 = (s6!=0.0f)?0.0f:y6;
    y7 = fmaf(DEC, y7, a1.w); s7 = (y7 >= 1.0f) ? 1.0f : 0.0f; y7 = (s7!=0.0f)?0.0f:y7;

    if (t >= t0) {
      unsigned int lo = 0, hi = 0;
      lo |= ((unsigned int)(int)(s0 - p0) & 0xffu);
      lo |= ((unsigned int)(int)(s1 - p1) & 0xffu) << 8;
      lo |= ((unsigned int)(int)(s2 - p2) & 0xffu) << 16;
      lo |= ((unsigned int)(int)(s3 - p3) & 0xffu) << 24;
      hi |= ((unsigned int)(int)(s4 - p4) & 0xffu);
      hi |= ((unsigned int)(int)(s5 - p5) & 0xffu) << 8;
      hi |= ((unsigned int)(int)(s6 - p6) & 0xffu) << 16;
      hi |= ((unsigned int)(int)(s7 - p7) & 0xffu) << 24;
      if (t == 0) { lo = 0u; hi = 0u; }     // delta_encode: d[0] = 0
      uint2 v; v.x = lo; v.y = hi;
      *reinterpret_cast<uint2*>(db + (long)t * tsb) = v;
    }
    p0=s0; p1=s1; p2=s2; p3=s3; p4=s4; p5=s5; p6=s6; p7=s7;
    a0 = n0; a1 = n1;
  }
}

// ---------------------------------------------------------------------------
// Kernel A-fused (FALLBACK when ws_size < split requirement): r10's proven
// conv1+relu+LIF1+delta kernel (77 us). Unchanged.
// ---------------------------------------------------------------------------
__global__ void __launch_bounds__(512) convlif_kernel(
    const float* __restrict__ xT, const float* __restrict__ w1,
    const float* __restrict__ b1, signed char* __restrict__ d8) {
  __shared__ float bufA[80 * 64];
  __shared__ float bufB[80 * 64];
  __shared__ float dump[16 * 64];
  __shared__ __align__(16) unsigned char st[8][512];
  const int tid = threadIdx.x;
  const int bid = blockIdx.x;
  const int chunk = bid & 7;
  const int rest  = bid >> 3;
  const int h = rest & 63;
  const int b = rest >> 6;
  const int w  = tid & 63;
  const int co = __builtin_amdgcn_readfirstlane(tid >> 6);

  const int tstore = chunk * 48;
  const int ts     = chunk ? tstore - 16 : 0;
  const int te     = tstore + 48 < T ? tstore + 48 : T;
  const int nsup   = (te - ts + 7) / 8;

  float wt[2][5][5];
  float win[2][5][4];
#pragma unroll
  for (int ci = 0; ci < 2; ++ci)
#pragma unroll
    for (int dh = 0; dh < 5; ++dh) {
      int hh = h + dh - 2;
      bool hv = (hh >= 0) && (hh < H);
      int hc = hh < 0 ? 0 : (hh > H - 1 ? H - 1 : hh);
#pragma unroll
      for (int dt = 0; dt < 5; ++dt)
        wt[ci][dt][dh] = hv ? w1[((co * 2 + ci) * 5 + dt) * 5 + dh] : 0.0f;
      const float* bp = xT + ((long)((b * 2 + ci) * T)) * HW + hc * 64 + w;
      win[ci][dh][2] = (ts >= 2) ? bp[(long)(ts - 2) * HW] : 0.0f;
      win[ci][dh][3] = (ts >= 1) ? bp[(long)(ts - 1) * HW] : 0.0f;
      win[ci][dh][0] = bp[(long)(ts + 0) * HW];
      win[ci][dh][1] = bp[(long)(ts + 1) * HW];
    }
  float bias = b1[co];

  int cdesc[3];
#pragma unroll
  for (int i = 0; i < 3; ++i) {
    int r = (tid >> 4) + 32 * i;
    if (r > 79) r = 79;
    int j   = r / 10;
    int rem = r - j * 10;
    int ci  = rem / 5;
    int dh  = rem - ci * 5;
    int hh = h + dh - 2;
    int hc = hh < 0 ? 0 : (hh > H - 1 ? H - 1 : hh);
    cdesc[i] = (((b * 2 + ci) * T) * HW + hc * 64 + (tid & 15) * 4) | (j << 27);
  }
  const int dro0 = (0 * 32 + co * 4) * 64;
  const int dro1 = (1 * 32 + co * 4) * 64;
  const int dro2 = (co < 4) ? (2 * 32 + co * 4) * 64 : ((co - 4) * 4) * 64;
  float* const pad = &dump[0];

  {
    int tau0 = ts + 2 + (cdesc[0] >> 27); if (tau0 > T - 1) tau0 = T - 1;
    int tau1 = ts + 2 + (cdesc[1] >> 27); if (tau1 > T - 1) tau1 = T - 1;
    int tau2 = ts + 2 + (cdesc[2] >> 27); if (tau2 > T - 1) tau2 = T - 1;
    gload_lds16(xT + (long)(cdesc[0] & 0x07ffffff) + (long)tau0 * HW, bufA + dro0);
    gload_lds16(xT + (long)(cdesc[1] & 0x07ffffff) + (long)tau1 * HW, bufA + dro1);
    gload_lds16(xT + (long)(cdesc[2] & 0x07ffffff) + (long)tau2 * HW,
                (co < 4 ? bufA : pad) + dro2);
  }

  asm volatile("s_waitcnt vmcnt(0)" ::: "memory");
  __builtin_amdgcn_s_barrier();
  asm volatile("" ::: "memory");

  signed char* const d8row = d8 + ((long)(b * T)) * (HW * C1) + h * 512;
  const int fl_u  = tid >> 5;
  const int fl_cb = (tid & 31) * 16;
  const int stw   = w * 8 + co;

  float y = 0.0f, sprev = 0.0f;
  for (int k = 0; k < nsup; ++k) {
    asm volatile("s_waitcnt lgkmcnt(0)" ::: "memory");
    __builtin_amdgcn_s_barrier();
    asm volatile("" ::: "memory");

    if (k + 1 < nsup) {
      int bs = ts + 2 + 8 * (k + 1);
      float* nb = ((k + 1) & 1) ? bufB : bufA;
      int tau0 = bs + (cdesc[0] >> 27); if (tau0 > T - 1) tau0 = T - 1;
      int tau1 = bs + (cdesc[1] >> 27); if (tau1 > T - 1) tau1 = T - 1;
      int tau2 = bs + (cdesc[2] >> 27); if (tau2 > T - 1) tau2 = T - 1;
      gload_lds16(xT + (long)(cdesc[0] & 0x07ffffff) + (long)tau0 * HW, nb + dro0);
      gload_lds16(xT + (long)(cdesc[1] & 0x07ffffff) + (long)tau1 * HW, nb + dro1);
      gload_lds16(xT + (long)(cdesc[2] & 0x07ffffff) + (long)tau2 * HW,
                  (co < 4 ? nb : pad) + dro2);
      asm volatile("s_waitcnt vmcnt(3)" ::: "memory");
    } else {
      asm volatile("s_waitcnt vmcnt(0)" ::: "memory");
    }

    if (k > 0 && tid < 256) {
      int t = ts + 8 * (k - 1) + fl_u;
      if (t >= tstore && t < te) {
        uint4 v = *reinterpret_cast<const uint4*>(&st[fl_u][fl_cb]);
        *reinterpret_cast<uint4*>(d8row + (long)t * (HW * C1) + fl_cb) = v;
      }
    }

    asm volatile("s_waitcnt lgkmcnt(0)" ::: "memory");
    __builtin_amdgcn_s_barrier();
    asm volatile("" ::: "memory");

    float* lb = (k & 1) ? bufB : bufA;
    {
      int bufstart = ts + 2 + 8 * k;
      int rz0 = (T - bufstart) * 10;
      if (rz0 < 80) {
        if (rz0 < 0) rz0 = 0;
        for (int r = rz0 + co; r < 80; r += 8) lb[r * 64 + w] = 0.0f;
        asm volatile("s_waitcnt lgkmcnt(0)" ::: "memory");
        __builtin_amdgcn_s_barrier();
        asm volatile("" ::: "memory");
      }
    }

    const int t0s = ts + 8 * k;
#pragma unroll
    for (int u = 0; u < 8; ++u) {
      int t = t0s + u;
      float fr[2][5];
#pragma unroll
      for (int ci = 0; ci < 2; ++ci)
#pragma unroll
        for (int dh = 0; dh < 5; ++dh)
          fr[ci][dh] = lb[(u * 10 + ci * 5 + dh) * 64 + w];

      float ac0 = 0.f, ac1 = 0.f, ac2 = 0.f, ac3 = 0.f;
#pragma unroll
      for (int ci = 0; ci < 2; ++ci)
#pragma unroll
        for (int dt = 0; dt < 5; ++dt)
#pragma unroll
          for (int dh = 0; dh < 5; ++dh) {
            const int q = (ci * 25 + dt * 5 + dh) & 3;
            float tap = (dt < 4) ? win[ci][dh][(u + 2 + dt) & 3] : fr[ci][dh];
            float p = tap * wt[ci][dt][dh];
            if (q == 0) ac0 += p;
            else if (q == 1) ac1 += p;
            else if (q == 2) ac2 += p;
            else ac3 += p;
          }
      float a = ((ac0 + ac1) + (ac2 + ac3)) + bias;
      a = fmaxf(a, 0.0f);
      y = fmaf(DEC, y, a);
      float s = (y >= 1.0f) ? 1.0f : 0.0f;
      float dlt = (t == 0) ? 0.0f : (s - sprev);
      st[u][stw] = (unsigned char)(signed char)dlt;
      sprev = s;
      y = (s != 0.0f) ? 0.0f : y;
#pragma unroll
      for (int ci = 0; ci < 2; ++ci)
#pragma unroll
        for (int dh = 0; dh < 5; ++dh)
          win[ci][dh][(u + 2) & 3] = fr[ci][dh];
    }
  }

  asm volatile("s_waitcnt lgkmcnt(0)" ::: "memory");
  __builtin_amdgcn_s_barrier();
  asm volatile("" ::: "memory");
  if (tid < 256) {
    int t = ts + 8 * (nsup - 1) + fl_u;
    if (t >= tstore && t < te) {
      uint4 v = *reinterpret_cast<const uint4*>(&st[fl_u][fl_cb]);
      *reinterpret_cast<uint4*>(d8row + (long)t * (HW * C1) + fl_cb) = v;
    }
  }
}

// ---------------------------------------------------------------------------
// Kernel B: deconv(2x2,s2) + bias + relu + conv2(1x1) + LIF2 -> out
// d8 [b][t][hw][ci]: one 8B uint2 load per pair-step, prefetched 1 iter ahead.
// out layout [B,2,H',W',T']; LDS-staged transposed flush. 25 chunks of 28.
// ---------------------------------------------------------------------------
__global__ void __launch_bounds__(64) stage2_kernel(
    const signed char* __restrict__ d8, const float* __restrict__ dw,
    const float* __restrict__ db, const float* __restrict__ cw,
    const float* __restrict__ cb, float* __restrict__ out) {
  __shared__ float SB[2][64][17];
  int bid   = blockIdx.x;
  int chunk = bid % 25;
  int rest  = bid / 25;
  int hp = rest & 127;
  int b  = rest >> 7;
  int wp = threadIdx.x;

  int h  = hp >> 1;
  int kh = 1 - (hp & 1);

  float dwk0[2][8], dwk1[2][8];
#pragma unroll
  for (int c = 0; c < 2; ++c)
#pragma unroll
    for (int ci = 0; ci < 8; ++ci) {
      dwk0[c][ci] = dw[((c * 8 + ci) * 2 + 0) * 2 + kh];
      dwk1[c][ci] = dw[((c * 8 + ci) * 2 + 1) * 2 + kh];
    }
  float db0 = db[0], db1 = db[1];
  float cw00 = cw[0], cw01 = cw[1], cw10 = cw[2], cw11 = cw[3];
  float cb0 = cb[0], cb1 = cb[1];

  int t0 = chunk * 28;
  int t1 = t0 + 28;
  int tw = (t0 - 16 > 0) ? t0 - 16 : 0;

  const signed char* dbase = d8 + (((long)b * T) * HW + h * 64 + wp) * C1;
  const long tstride = (long)HW * C1;
  float* outb = out + ((long)b * 2 * HO) * (long)(WO * TO);

  float y0 = 0.0f, y1 = 0.0f;
  uint2 dc = *reinterpret_cast<const uint2*>(dbase + (long)(tw >> 1) * tstride);
  for (int tp = tw; tp < t1; tp += 2) {
    int tn = (tp + 2 < t1) ? ((tp + 2) >> 1) : ((t1 - 1) >> 1);
    uint2 dn = *reinterpret_cast<const uint2*>(dbase + (long)tn * tstride);

    float dv[8];
#pragma unroll
    for (int ci = 0; ci < 4; ++ci) {
      dv[ci]     = (float)(signed char)((dc.x >> (8 * ci)) & 0xff);
      dv[ci + 4] = (float)(signed char)((dc.y >> (8 * ci)) & 0xff);
    }

#pragma unroll
    for (int par = 0; par < 2; ++par) {
      int tpp = tp + par;
      float v0 = db0, v1 = db1;
      if (par == 0) {
#pragma unroll
        for (int ci = 0; ci < 8; ++ci) {
          v0 = fmaf(dv[ci], dwk1[0][ci], v0);
          v1 = fmaf(dv[ci], dwk1[1][ci], v1);
        }
      } else {
#pragma unroll
        for (int ci = 0; ci < 8; ++ci) {
          v0 = fmaf(dv[ci], dwk0[0][ci], v0);
          v1 = fmaf(dv[ci], dwk0[1][ci], v1);
        }
      }
      v0 = fmaxf(v0, 0.0f);
      v1 = fmaxf(v1, 0.0f);
      float u0 = fmaf(cw00, v0, fmaf(cw01, v1, cb0));
      float u1 = fmaf(cw10, v0, fmaf(cw11, v1, cb1));
      y0 = fmaf(DEC, y0, u0);
      y1 = fmaf(DEC, y1, u1);
      float s0 = (y0 >= 1.0f) ? 1.0f : 0.0f;
      float s1 = (y1 >= 1.0f) ? 1.0f : 0.0f;
      y0 = (s0 != 0.0f) ? 0.0f : y0;
      y1 = (s1 != 0.0f) ? 0.0f : y1;

      if (tpp >= t0) {
        int k = (tpp - t0) & 15;
        SB[0][wp][k] = s0;
        SB[1][wp][k] = s1;
        if (par == 1 && (k == 15 || tpp == t1 - 1)) {
          __syncthreads();
          int Kc  = k + 1;
          int t0f = tpp - k;
#pragma unroll
          for (int o = 0; o < 2; ++o) {
            float* ob = outb + ((long)(o * HO + hp)) * (long)(WO * TO);
#pragma unroll
            for (int i = 0; i < 4; ++i) {
              int idx = (i << 6) + wp;
              int r   = idx >> 2;
              int c   = (idx & 3) << 2;
              if (c < Kc) {
                float4 vv;
                vv.x = SB[o][r][c + 0];
                vv.y = SB[o][r][c + 1];
                vv.z = SB[o][r][c + 2];
                vv.w = SB[o][r][c + 3];
                *reinterpret_cast<float4*>(ob + (long)r * TO + (t0f + c)) = vv;
              }
            }
          }
          __syncthreads();
        }
      }
    }
    dc = dn;
  }
}

// ---------------------------------------------------------------------------
extern "C" void kernel_launch(void* const* d_in, const int* in_sizes, int n_in,
                              void* d_out, int out_size, void* d_ws, size_t ws_size,
                              hipStream_t stream) {
  const float* x  = (const float*)d_in[0];
  const float* w1 = (const float*)d_in[1];
  const float* b1 = (const float*)d_in[2];
  const float* dw = (const float*)d_in[3];
  const float* db = (const float*)d_in[4];
  const float* cw = (const float*)d_in[5];
  const float* cb = (const float*)d_in[6];
  float* out = (float*)d_out;

  const size_t xT_b = (size_t)4 * B * CIN * T * HW;   // 22.94 MB
  const size_t d8_b = (size_t)B * T * HW * C1;        // 22.94 MB
  const size_t A_b  = (size_t)4 * B * T * HW * C1;    // 91.75 MB

  float* xT = (float*)d_ws;
  signed char* d8 = (signed char*)d_ws + xT_b;

  // 1) transpose x -> xT
  transpose_kernel<<<dim3(B * CIN * H * 6), dim3(256), 0, stream>>>(x, xT);

  if (ws_size >= xT_b + d8_b + A_b) {
    // SPLIT PATH: parallel conv -> A, streaming LIF -> d8
    float* A = (float*)((char*)d_ws + xT_b + d8_b);
    convpar_kernel<<<dim3(B * 30 * H), dim3(512), 0, stream>>>(xT, w1, b1, A);
    lif_kernel<<<dim3(B * 16 * 8), dim3(256), 0, stream>>>(A, d8);
  } else {
    // FALLBACK: r10 fused kernel (ws too small for A)
    convlif_kernel<<<dim3(B * H * 8), dim3(512), 0, stream>>>(xT, w1, b1, d8);
  }

  // 3) deconv+relu+conv2(1x1)+LIF2 -> out
  stage2_kernel<<<dim3(B * HO * 25), dim3(64), 0, stream>>>(d8, dw, db, cw, cb, out);
}